// Round 11
// baseline (198.559 us; speedup 1.0000x reference)
//
#include <hip/hip_runtime.h>
#include <stdint.h>

// ROUND-11: R10 (barrier-skewed dual-matrix block) with the skew barriers
// hardened: raw __builtin_amdgcn_s_barrier() in the wave-divergent skew
// prologue/epilogue (s_barrier is arrival-counted; __syncthreads() in
// non-block-uniform control flow risks compiler convergence miscompiles).
// All data-carrying barriers remain __syncthreads() at uniform points.
//
// Mechanism (R9 evidence): MfmaUtil(49)+VALUBusy(45) ~= wall -> the two
// co-resident waves/SIMD are phase-locked; MFMA and VALU never overlap.
// One 512-thr block owns TWO matrices (waves 0-3 mat0, 4-7 mat1; disjoint
// LDS planes + red slots). Per-iter schedule = 4 barrier-terminated segments
//   STG  : gradprox + stage            (pure VALU)
//   HEAD : afm,m2,m3 + T3 primary      (4 MFMA units)
//   TAIL : m6,m9,m12,m15 + T15 primary (5 MFMA units)
//   FRONT: trace + m30,m45,m60,m63acc  (4 MFMA units + VALU)
// mat1 runs 2 barrier-slots late (198 barriers per wave, both halves) ->
// each SIMD holds one mat0-wave and one mat1-wave locked 2 segments apart:
// STG(VALU) co-resides with TAIL(MFMA) deterministically.
//
// Carried (verified): R9 column-strided ownership + register-local gradprox
// (acc63 f32) + identity-one-hot chain head; R8 pi-relabeled fragments
// (permlane-free macc_to_af); R7 med3 prox + setprio; R6 3-plane chain
//   T(m): m2,m3 ; T3: m6,m9,m12,m15,m63 ; T15: m30,m45,m60.
// Plane format: bf16, stride 64, XOR-swizzled:
//   off(X,Y) = X*64 + (((Y>>3) ^ (X&7))<<3) + (Y&7); Y-axis pi-labeled,
//   pi(16b+4g+j) = 32(b>>1)+8g+4(b&1)+j.
#define PL 4096  // shorts per plane

typedef unsigned int u32;
typedef unsigned short u16;
typedef float f32x4 __attribute__((ext_vector_type(4)));
typedef short short8 __attribute__((ext_vector_type(8)));

__device__ __forceinline__ u32 prm(u32 a, u32 b, u32 s) {
  return __builtin_amdgcn_perm(a, b, s);
}
__device__ __forceinline__ u32 pk(float f0, float f1) {  // {bf16 f0, bf16 f1}
  return prm(__float_as_uint(f1), __float_as_uint(f0), 0x07060302u);
}
__device__ __forceinline__ float rlo(u32 w) { return __uint_as_float(w << 16); }
__device__ __forceinline__ float rhi(u32 w) {
  return __uint_as_float(w & 0xffff0000u);
}
__device__ __forceinline__ short8 mk8(u32 w0, u32 w1, u32 w2, u32 w3) {
  union {
    u32 w[4];
    short8 s;
  } u;
  u.w[0] = w0;
  u.w[1] = w1;
  u.w[2] = w2;
  u.w[3] = w3;
  return u.s;
}
__device__ __forceinline__ void dot8(short8 a, short8 b, float& part) {
  union {
    short8 s;
    u32 w[4];
  } ua, ub;
  ua.s = a;
  ub.s = b;
#pragma unroll
  for (int w = 0; w < 4; ++w) {
    part = fmaf(rlo(ua.w[w]), rlo(ub.w[w]), part);
    part = fmaf(rhi(ua.w[w]), rhi(ub.w[w]), part);
  }
}
__device__ __forceinline__ f32x4 MF(short8 a, short8 b, f32x4 c) {
  return __builtin_amdgcn_mfma_f32_16x16x32_bf16(a, b, c, 0, 0, 0);
}

struct AF {
  short8 a0, a1;
};  // A-frags of the wave's row band: pi-positions [0,32) and [32,64)
struct BF8 {
  short8 b[4][2];
};  // B-frags: 4 col tiles x 2 k-halves (pi-positions)

// Mirror acc tiles b: lane = row 16w+l15; P0[b]=cols 16b+4g+{0,1},
// P1[b]=cols 16b+4g+{2,3}. pi puts these exactly at a0/a1 word slots.
__device__ __forceinline__ AF macc_to_af(const f32x4 (&m)[4]) {
  u32 P0[4], P1[4];
#pragma unroll
  for (int b = 0; b < 4; ++b) {
    P0[b] = pk(m[b][0], m[b][1]);
    P1[b] = pk(m[b][2], m[b][3]);
  }
  AF r;
  r.a0 = mk8(P0[0], P1[0], P0[1], P1[1]);
  r.a1 = mk8(P0[2], P1[2], P0[3], P1[3]);
  return r;
}

__global__ __launch_bounds__(512, 2) void dag_iter_kernel(
    const float* __restrict__ adj, float* __restrict__ out) {
  __shared__ __align__(16) u16 BUF[6 * PL];
  __shared__ float red[8];

  const int tid = (int)threadIdx.x;
  const int lane = tid & 63;
  const int wv = tid >> 6;  // 0..7
  const int mat = wv >> 2;  // matrix 0/1 within the block
  const int w = wv & 3;     // row band 0..3 within the matrix
  const int l15 = lane & 15;
  const int grp = lane >> 4;
  const int l7 = l15 & 7;

  u16* SM = BUF + mat * 3 * PL;  // T(m)
  u16* P1 = SM + PL;             // T3
  u16* P2 = SM + 2 * PL;         // T15

  const int c = 16 * w + l15;  // owned column
  int rb[4][2];
#pragma unroll
  for (int b = 0; b < 4; ++b)
#pragma unroll
    for (int kh = 0; kh < 2; ++kh)
      rb[b][kh] = (16 * b + l15) * 64 + ((((kh << 2) + grp) ^ l7) << 3);
  int sT[4];
#pragma unroll
  for (int b = 0; b < 4; ++b)
    sT[b] = (16 * b + l15) * 64 +
            ((((grp + ((w >> 1) << 2)) ^ ((16 * b + l15) & 7))) << 3) +
            ((w & 1) << 2);
  int stT[2];
#pragma unroll
  for (int h = 0; h < 2; ++h)
    stT[h] = c * 64 + ((((h << 2) + grp) ^ (c & 7)) << 3);

  // afI: one-hot identity A-fragment, 1.0bf16 at pi-position pi(c).
  AF afI;
  {
    const bool mine = (grp == (l15 >> 2));
    const int s = ((w & 1) << 2) + (l15 & 3);  // slot 0..7
    const u32 onev = (s & 1) ? 0x3F800000u : 0x00003F80u;
    u32 ww[4];
#pragma unroll
    for (int k = 0; k < 4; ++k) ww[k] = (mine && ((s >> 1) == k)) ? onev : 0u;
    short8 hot = mk8(ww[0], ww[1], ww[2], ww[3]);
    short8 zero = mk8(0u, 0u, 0u, 0u);
    afI.a0 = (w < 2) ? hot : zero;
    afI.a1 = (w < 2) ? zero : hot;
  }

  // x[b][j] = x[r][c], r = 16b+4g+j.
  const float* src = adj + (size_t)(2 * blockIdx.x + mat) * 4096;
  float x[4][4], sc[4][4];
#pragma unroll
  for (int b = 0; b < 4; ++b)
#pragma unroll
    for (int j = 0; j < 4; ++j) {
      float v = src[(16 * b + 4 * grp + j) * 64 + c];
      x[b][j] = v;
      sc[b][j] = (v > 0.5f) ? v : 0.0f;
    }
  float alpha = 0.0f;
  AF af;           // af(m15): TAIL -> FRONT
  AF af3;          // af(m3): HEAD -> TAIL
  BF8 bf3;         // B-frags of m3 (T3): TAIL -> FRONT (m63)
  f32x4 acc63[4];  // m63 mirror acc (f32), FRONT -> STG

  auto loadBF = [&](const u16* P) {
    BF8 f;
#pragma unroll
    for (int b = 0; b < 4; ++b) {
      f.b[b][0] = *(const short8*)(P + rb[b][0]);
      f.b[b][1] = *(const short8*)(P + rb[b][1]);
    }
    return f;
  };
  auto mirrorAF = [&](const AF& a, const BF8& bf) {  // rows of A*M -> regs
    const f32x4 Z = {0.0f, 0.0f, 0.0f, 0.0f};
    f32x4 m[4];
    __builtin_amdgcn_s_setprio(1);
#pragma unroll
    for (int b = 0; b < 4; ++b) {
      m[b] = MF(bf.b[b][0], a.a0, Z);
      m[b] = MF(bf.b[b][1], a.a1, m[b]);
    }
    __builtin_amdgcn_s_setprio(0);
    return macc_to_af(m);
  };
  auto primaryT = [&](const AF& a, const BF8& bf, u16* P) {  // cols -> T-plane
    const f32x4 Z = {0.0f, 0.0f, 0.0f, 0.0f};
    f32x4 p[4];
    __builtin_amdgcn_s_setprio(1);
#pragma unroll
    for (int b = 0; b < 4; ++b) {
      p[b] = MF(a.a0, bf.b[b][0], Z);
      p[b] = MF(a.a1, bf.b[b][1], p[b]);
    }
    __builtin_amdgcn_s_setprio(0);
#pragma unroll
    for (int b = 0; b < 4; ++b)
      *(uint2*)(P + sT[b]) =
          make_uint2(pk(p[b][0], p[b][1]), pk(p[b][2], p[b][3]));
  };
  auto traceP = [&](const AF& a, const BF8& bf) {  // tr(m30) from m15 frags
    short8 c0s = bf.b[0][0], c1s = bf.b[0][1];
    if (w == 1) {
      c0s = bf.b[1][0];
      c1s = bf.b[1][1];
    } else if (w == 2) {
      c0s = bf.b[2][0];
      c1s = bf.b[2][1];
    } else if (w == 3) {
      c0s = bf.b[3][0];
      c1s = bf.b[3][1];
    }
    float part = 0.0f;
    dot8(a.a0, c0s, part);
    dot8(a.a1, c1s, part);
#pragma unroll
    for (int off = 1; off < 64; off <<= 1) part += __shfl_xor(part, off);
    if (lane == 0) red[(mat << 2) + w] = part;
  };

  auto prox = [&](float til[4][4]) {
#pragma unroll
    for (int b = 0; b < 4; ++b)
#pragma unroll
      for (int j = 0; j < 4; ++j) {
        float ax = fabsf(til[b][j]) - 2e-5f;
        x[b][j] = fminf(fmaxf(ax, 0.0f), 1.0f);  // -> v_med3_f32
      }
  };
  auto stageW = [&]() {  // m = I + x.*x/64 -> T(m)-plane (SM), 2x b128 + bar
    float m[4][4];
#pragma unroll
    for (int b = 0; b < 4; ++b)
#pragma unroll
      for (int j = 0; j < 4; ++j)
        m[b][j] = fmaf(x[b][j] * x[b][j], 0.015625f,
                       (b == w && 4 * grp + j == l15) ? 1.0f : 0.0f);
#pragma unroll
    for (int h = 0; h < 2; ++h)
      *(short8*)(SM + stT[h]) =
          mk8(pk(m[2 * h][0], m[2 * h][1]), pk(m[2 * h][2], m[2 * h][3]),
              pk(m[2 * h + 1][0], m[2 * h + 1][1]),
              pk(m[2 * h + 1][2], m[2 * h + 1][3]));
    __syncthreads();  // STG bar
  };
  auto gradprox = [&]() {  // m63^T patch = acc63 f32 regs; alpha from red
    const int rbase = mat << 2;
    float tr = red[rbase] + red[rbase + 1] + red[rbase + 2] + red[rbase + 3];
    alpha = fmaf(0.01f, tr * 0.015625f - 1.0f, alpha);
    const float a2 = alpha * 0.03125f;  // 2*alpha/64
    float til[4][4];
#pragma unroll
    for (int b = 0; b < 4; ++b)
#pragma unroll
      for (int j = 0; j < 4; ++j) {
        float g = fmaf(a2 * x[b][j], acc63[b][j], -sc[b][j]);
        til[b][j] = fmaf(-0.01f, g, x[b][j]);
      }
    prox(til);
  };

  auto segHEAD = [&]() {  // from SM=T(m): afm, m2, m3; T3 primary
    BF8 bm = loadBF(SM);
    AF afm = mirrorAF(afI, bm);  // rows of m via identity one-hot
    AF af2 = mirrorAF(afm, bm);  // m2
    af3 = mirrorAF(af2, bm);     // m3 rows (carried to TAIL)
    primaryT(af2, bm, P1);       // m3 cols -> T3
    __syncthreads();             // HEAD bar
  };
  auto segTAIL = [&]() {  // B=T3: m6..m15; T15 primary
    bf3 = loadBF(P1);
    AF af6 = mirrorAF(af3, bf3);   // m6
    AF af9 = mirrorAF(af6, bf3);   // m9
    AF af12 = mirrorAF(af9, bf3);  // m12
    af = mirrorAF(af12, bf3);      // m15 rows (carried to FRONT)
    primaryT(af12, bf3, P2);       // m15 cols -> T15
    __syncthreads();               // TAIL bar
  };
  auto segFRONT = [&]() {  // B=T15: trace, m30,m45,m60; m63 mirror acc
    BF8 b15 = loadBF(P2);
    traceP(af, b15);  // red[(mat<<2)+w] = band part of tr(m30)
    AF af30 = mirrorAF(af, b15);
    AF af45 = mirrorAF(af30, b15);
    AF af60 = mirrorAF(af45, b15);
    const f32x4 Z = {0.0f, 0.0f, 0.0f, 0.0f};
    __builtin_amdgcn_s_setprio(1);
#pragma unroll
    for (int b = 0; b < 4; ++b) {
      acc63[b] = MF(bf3.b[b][0], af60.a0, Z);
      acc63[b] = MF(bf3.b[b][1], af60.a1, acc63[b]);
    }
    __builtin_amdgcn_s_setprio(0);
    __syncthreads();  // FRONT bar (also syncs red for the next STG)
  };

  // ---- skew: mat1 runs 2 barrier-slots late (raw s_barrier: legal in
  // wave-divergent flow; arrival-counted; no data dependence here) ----
  if (mat) {
    __builtin_amdgcn_s_barrier();
    __builtin_amdgcn_s_barrier();
  }

  // STG0: alpha == 0 -> grad = -scores
  {
    float til[4][4];
#pragma unroll
    for (int b = 0; b < 4; ++b)
#pragma unroll
      for (int j = 0; j < 4; ++j) til[b][j] = fmaf(0.01f, sc[b][j], x[b][j]);
    prox(til);
    stageW();
  }
  segHEAD();
  segTAIL();
  // ---- iterations 1..48 ----
  for (int it = 0; it < 48; ++it) {
    segFRONT();
    gradprox();
    stageW();
    segHEAD();
    segTAIL();
  }
  // ---- iteration 49: front + gradprox, no trailing stage/chain ----
  segFRONT();
  gradprox();

  float* dst = out + (size_t)(2 * blockIdx.x + mat) * 4096;
#pragma unroll
  for (int b = 0; b < 4; ++b)
#pragma unroll
    for (int j = 0; j < 4; ++j) {
      float v = x[b][j];
      dst[(16 * b + 4 * grp + j) * 64 + c] = (v > 0.5f) ? v : 0.0f;
    }

  // ---- skew epilogue: mat0 matches mat1's trailing barriers ----
  if (mat == 0) {
    __builtin_amdgcn_s_barrier();
    __builtin_amdgcn_s_barrier();
  }
}

extern "C" void kernel_launch(void* const* d_in, const int* in_sizes, int n_in,
                              void* d_out, int out_size, void* d_ws,
                              size_t ws_size, hipStream_t stream) {
  const float* adj = (const float*)d_in[0];
  float* out = (float*)d_out;
  const int nbatch = in_sizes[0] / 4096;  // 512
  dag_iter_kernel<<<nbatch / 2, 512, 0, stream>>>(adj, out);
}